// Round 3
// baseline (54.359 us; speedup 1.0000x reference)
//
#include <hip/hip_runtime.h>
#include <hip/hip_cooperative_groups.h>
#include <math.h>

namespace cg = cooperative_groups;

#define BN   4096
#define GX   16          // i-tiles of 256 rows
#define GY   32          // j-tiles of 128 rows
#define TJ   128         // j-tile size
#define NB   (GX * GY)   // 512 partial slots

// ln(1e-4)
#define LOGE  (-9.210340371976184f)
#define EPSF  (1e-4f)
// sT = 2*eps*ln(eps), constant for every row
#define STC   (2.0f * EPSF * LOGE)

// partial[bid] = {a1, a3, c2, c0}
__global__ __launch_bounds__(256) void k_all(const float* __restrict__ src,
                                             const int* __restrict__ tgt,
                                             float* __restrict__ partial,
                                             float* __restrict__ out) {
    __shared__ float4 js[TJ];     // LS0, LS1, LS2, (float)class  for j-row
    __shared__ int    sc[3];      // j-tile class counts
    __shared__ float4 wred[4];    // per-wave partial sums
    int tid = threadIdx.x;
    int bx = blockIdx.x, by = blockIdx.y;

    if (tid < 3) sc[tid] = 0;

    // ---- this thread's i-row data (registers only) ----
    int i = bx * 256 + tid;
    float S0, S1, S2, aI, sumLS_i, L0i, L1i, L2i;
    int ti;
    {
        float x0 = src[3*i], x1 = src[3*i+1], x2 = src[3*i+2];
        float m  = fmaxf(x0, fmaxf(x1, x2));
        float e0 = expf(x0 - m), e1 = expf(x1 - m), e2 = expf(x2 - m);
        float s  = e0 + e1 + e2;
        float inv = 1.0f / s;
        S0 = e0 * inv; S1 = e1 * inv; S2 = e2 * inv;
        float ls = logf(s);
        L0i = x0 - m - ls; L1i = x1 - m - ls; L2i = x2 - m - ls;
        sumLS_i = L0i + L1i + L2i;
        float sS = S0 * L0i + S1 * L1i + S2 * L2i;
        ti = tgt[i];
        aI = sS - STC;                 // sS_i - sT
    }
    float tif = (float)ti;
    float tdSame = aI + 2.0f * EPSF * LOGE;     // aI + T_i.LT_j (same class)
    float tdDiff = aI + (1.0f + EPSF) * LOGE;   // (diff class)
    // dw = w - S  where w_k = eps + (1-eps)[k==ti]; e3 = |aI + dw.L|
    float dw0 = EPSF + ((ti == 0) ? (1.0f - EPSF) : 0.0f) - S0;
    float dw1 = EPSF + ((ti == 1) ? (1.0f - EPSF) : 0.0f) - S1;
    float dw2 = EPSF + ((ti == 2) ? (1.0f - EPSF) : 0.0f) - S2;
    // loss_2 per-class |u_ik|
    float base = EPSF * (2.0f * LOGE - sumLS_i);
    float au0 = fabsf(base + (1.0f - EPSF) * (((ti == 0) ? 0.f : LOGE) - L0i));
    float au1 = fabsf(base + (1.0f - EPSF) * (((ti == 1) ? 0.f : LOGE) - L1i));
    float au2 = fabsf(base + (1.0f - EPSF) * (((ti == 2) ? 0.f : LOGE) - L2i));
    // loss_0 per-row (counted once: only by==0 blocks)
    float LSt = (ti == 0) ? L0i : ((ti == 1) ? L1i : L2i);
    float c0 = (by == 0) ? -(EPSF * sumLS_i + (1.0f - EPSF) * LSt) : 0.0f;

    __syncthreads();   // sc zeroed

    // ---- stage j-tile into LDS ----
    if (tid < TJ) {
        int j = by * TJ + tid;
        float x0 = src[3*j], x1 = src[3*j+1], x2 = src[3*j+2];
        float m  = fmaxf(x0, fmaxf(x1, x2));
        float e0 = expf(x0 - m), e1 = expf(x1 - m), e2 = expf(x2 - m);
        float s  = e0 + e1 + e2;
        float ls = logf(s);
        int tj = tgt[j];
        js[tid] = make_float4(x0 - m - ls, x1 - m - ls, x2 - m - ls, (float)tj);
        atomicAdd(&sc[tj], 1);
    }
    __syncthreads();

    // loss_2: local j-tile counts x per-class |u|
    float c2 = (float)sc[0] * au0 + (float)sc[1] * au1 + (float)sc[2] * au2;

    // ---- pair loop over j-tile ----
    float a1 = 0.f, a3 = 0.f;
    #pragma unroll 8
    for (int k = 0; k < TJ; ++k) {
        float4 L = js[k];                                        // broadcast
        float d   = fmaf(S0, L.x, fmaf(S1, L.y, S2 * L.z));      // S_i.LS_j
        float e3  = fmaf(dw0, L.x, fmaf(dw1, L.y, fmaf(dw2, L.z, aI)));
        float td  = (L.w == tif) ? tdSame : tdDiff;
        a1 += fabsf(td - d);
        a3 += fabsf(e3);
    }

    // ---- block reduction via wave shuffles ----
    for (int off = 32; off > 0; off >>= 1) {
        a1 += __shfl_down(a1, off);
        a3 += __shfl_down(a3, off);
        c2 += __shfl_down(c2, off);
        c0 += __shfl_down(c0, off);
    }
    int lane = tid & 63, wid = tid >> 6;
    if (lane == 0) wred[wid] = make_float4(a1, a3, c2, c0);
    __syncthreads();
    if (tid == 0) {
        float4 p = wred[0];
        #pragma unroll
        for (int w = 1; w < 4; ++w) {
            p.x += wred[w].x; p.y += wred[w].y;
            p.z += wred[w].z; p.w += wred[w].w;
        }
        partial[4*(by * GX + bx) + 0] = p.x;
        partial[4*(by * GX + bx) + 1] = p.y;
        partial[4*(by * GX + bx) + 2] = p.z;
        partial[4*(by * GX + bx) + 3] = p.w;
    }

    // ---- grid-wide sync, then block (0,0) finalizes ----
    cg::this_grid().sync();
    if (bx == 0 && by == 0) {
        double s1 = 0, s3 = 0, s2 = 0, s0d = 0;
        for (int p = tid; p < NB; p += 256) {
            float4 v = reinterpret_cast<const float4*>(partial)[p];
            s1 += (double)v.x; s3 += (double)v.y;
            s2 += (double)v.z; s0d += (double)v.w;
        }
        for (int off = 32; off > 0; off >>= 1) {
            s1  += __shfl_down(s1, off);
            s3  += __shfl_down(s3, off);
            s2  += __shfl_down(s2, off);
            s0d += __shfl_down(s0d, off);
        }
        __shared__ double d1[4], d3[4], d2[4], d0[4];
        if (lane == 0) { d1[wid] = s1; d3[wid] = s3; d2[wid] = s2; d0[wid] = s0d; }
        __syncthreads();
        if (tid == 0) {
            double t1 = d1[0]+d1[1]+d1[2]+d1[3];
            double t3 = d3[0]+d3[1]+d3[2]+d3[3];
            double t2 = d2[0]+d2[1]+d2[2]+d2[3];
            double t0 = d0[0]+d0[1]+d0[2]+d0[3];
            double n2 = (double)BN * (double)BN;
            double l0 = t0 / (double)BN;
            double l1 = (1e-4 + t1) / n2;
            double l2 = (1e-4 + t2) / n2;
            double l3 = (1e-4 + t3) / n2;
            out[0] = (float)((l0 + l1) + (l2 + l3));
            out[1] = (float)l0;
            out[2] = (float)l1;
            out[3] = (float)l2;
            out[4] = (float)l3;
        }
    }
}

extern "C" void kernel_launch(void* const* d_in, const int* in_sizes, int n_in,
                              void* d_out, int out_size, void* d_ws, size_t ws_size,
                              hipStream_t stream) {
    const float* src = (const float*)d_in[0];
    const int*   tgt = (const int*)d_in[1];
    float*       out = (float*)d_out;
    float*   partial = (float*)d_ws;    // NB*4 floats, fully rewritten every call

    void* args[] = { (void*)&src, (void*)&tgt, (void*)&partial, (void*)&out };
    hipLaunchCooperativeKernel((const void*)k_all, dim3(GX, GY), dim3(256),
                               args, 0, stream);
}

// Round 4
// 16.943 us; speedup vs baseline: 3.2082x; 3.2082x over previous
//
#include <hip/hip_runtime.h>
#include <math.h>

#define BN   4096
#define GX   16          // i-tiles of 256 rows
#define GY   32          // j-tiles of 128 rows
#define TJ   128         // j-tile size
#define NB   (GX * GY)   // 512 partial slots

// ln(1e-4)
#define LOGE  (-9.210340371976184f)
#define EPSF  (1e-4f)
// sT = 2*eps*ln(eps), constant for every row
#define STC   (2.0f * EPSF * LOGE)

__device__ __forceinline__ unsigned mixh(unsigned a, unsigned b,
                                         unsigned c, unsigned d) {
    return (a * 2654435761u) ^ (b * 2246822519u) ^
           (c * 3266489917u) ^ (d * 668265263u) ^ 0x53927609u;
}

// ws layout: NB slots x 8 words: [a1, a3, c2, c0, tag, pad, pad, pad]
__global__ __launch_bounds__(256) void k_all(const float* __restrict__ src,
                                             const int* __restrict__ tgt,
                                             unsigned* __restrict__ ws,
                                             float* __restrict__ out) {
    __shared__ float4 js[TJ];     // LS0, LS1, LS2, (float)class  for j-row
    __shared__ int    sc[3];      // j-tile class counts
    __shared__ float4 wred[4];    // per-wave partial sums
    int tid = threadIdx.x;
    int bx = blockIdx.x, by = blockIdx.y;

    if (tid < 3) sc[tid] = 0;

    // ---- this thread's i-row data (registers only) ----
    int i = bx * 256 + tid;
    float S0, S1, S2, aI, sumLS_i, L0i, L1i, L2i;
    int ti;
    {
        float x0 = src[3*i], x1 = src[3*i+1], x2 = src[3*i+2];
        float m  = fmaxf(x0, fmaxf(x1, x2));
        float e0 = expf(x0 - m), e1 = expf(x1 - m), e2 = expf(x2 - m);
        float s  = e0 + e1 + e2;
        float inv = 1.0f / s;
        S0 = e0 * inv; S1 = e1 * inv; S2 = e2 * inv;
        float ls = logf(s);
        L0i = x0 - m - ls; L1i = x1 - m - ls; L2i = x2 - m - ls;
        sumLS_i = L0i + L1i + L2i;
        float sS = S0 * L0i + S1 * L1i + S2 * L2i;
        ti = tgt[i];
        aI = sS - STC;                 // sS_i - sT
    }
    float tif = (float)ti;
    float tdSame = aI + 2.0f * EPSF * LOGE;     // aI + T_i.LT_j (same class)
    float tdDiff = aI + (1.0f + EPSF) * LOGE;   // (diff class)
    // dw = w - S where w_k = eps + (1-eps)[k==ti]; e3 = |aI + dw.L|
    float dw0 = EPSF + ((ti == 0) ? (1.0f - EPSF) : 0.0f) - S0;
    float dw1 = EPSF + ((ti == 1) ? (1.0f - EPSF) : 0.0f) - S1;
    float dw2 = EPSF + ((ti == 2) ? (1.0f - EPSF) : 0.0f) - S2;
    // loss_2 per-class |u_ik|
    float base = EPSF * (2.0f * LOGE - sumLS_i);
    float au0 = fabsf(base + (1.0f - EPSF) * (((ti == 0) ? 0.f : LOGE) - L0i));
    float au1 = fabsf(base + (1.0f - EPSF) * (((ti == 1) ? 0.f : LOGE) - L1i));
    float au2 = fabsf(base + (1.0f - EPSF) * (((ti == 2) ? 0.f : LOGE) - L2i));
    // loss_0 per-row (counted once: only by==0 blocks)
    float LSt = (ti == 0) ? L0i : ((ti == 1) ? L1i : L2i);
    float c0 = (by == 0) ? -(EPSF * sumLS_i + (1.0f - EPSF) * LSt) : 0.0f;

    __syncthreads();   // sc zeroed

    // ---- stage j-tile into LDS ----
    if (tid < TJ) {
        int j = by * TJ + tid;
        float x0 = src[3*j], x1 = src[3*j+1], x2 = src[3*j+2];
        float m  = fmaxf(x0, fmaxf(x1, x2));
        float e0 = expf(x0 - m), e1 = expf(x1 - m), e2 = expf(x2 - m);
        float s  = e0 + e1 + e2;
        float ls = logf(s);
        int tj = tgt[j];
        js[tid] = make_float4(x0 - m - ls, x1 - m - ls, x2 - m - ls, (float)tj);
        atomicAdd(&sc[tj], 1);
    }
    __syncthreads();

    // loss_2: local j-tile counts x per-class |u|
    float c2 = (float)sc[0] * au0 + (float)sc[1] * au1 + (float)sc[2] * au2;

    // ---- pair loop over j-tile ----
    float a1 = 0.f, a3 = 0.f;
    #pragma unroll 8
    for (int k = 0; k < TJ; ++k) {
        float4 L = js[k];                                        // broadcast
        float d   = fmaf(S0, L.x, fmaf(S1, L.y, S2 * L.z));      // S_i.LS_j
        float e3  = fmaf(dw0, L.x, fmaf(dw1, L.y, fmaf(dw2, L.z, aI)));
        float td  = (L.w == tif) ? tdSame : tdDiff;
        a1 += fabsf(td - d);
        a3 += fabsf(e3);
    }

    // ---- block reduction via wave shuffles ----
    for (int off = 32; off > 0; off >>= 1) {
        a1 += __shfl_down(a1, off);
        a3 += __shfl_down(a3, off);
        c2 += __shfl_down(c2, off);
        c0 += __shfl_down(c0, off);
    }
    int lane = tid & 63, wid = tid >> 6;
    if (lane == 0) wred[wid] = make_float4(a1, a3, c2, c0);
    __syncthreads();

    int bid = by * GX + bx;
    if (tid == 0) {
        float4 p = wred[0];
        #pragma unroll
        for (int w = 1; w < 4; ++w) {
            p.x += wred[w].x; p.y += wred[w].y;
            p.z += wred[w].z; p.w += wred[w].w;
        }
        unsigned w0 = __float_as_uint(p.x), w1 = __float_as_uint(p.y);
        unsigned w2 = __float_as_uint(p.z), w3 = __float_as_uint(p.w);
        unsigned* slot = ws + bid * 8;
        __hip_atomic_store(slot + 0, w0, __ATOMIC_RELAXED, __HIP_MEMORY_SCOPE_AGENT);
        __hip_atomic_store(slot + 1, w1, __ATOMIC_RELAXED, __HIP_MEMORY_SCOPE_AGENT);
        __hip_atomic_store(slot + 2, w2, __ATOMIC_RELAXED, __HIP_MEMORY_SCOPE_AGENT);
        __hip_atomic_store(slot + 3, w3, __ATOMIC_RELAXED, __HIP_MEMORY_SCOPE_AGENT);
        __hip_atomic_store(slot + 4, mixh(w0, w1, w2, w3),
                           __ATOMIC_RELEASE, __HIP_MEMORY_SCOPE_AGENT);
    }

    // ---- last block gathers all slots (hash-validated spin) & finalizes ----
    if (bid == NB - 1) {
        double s1 = 0, s3 = 0, s2 = 0, s0d = 0;
        for (int s = tid; s < NB; s += 256) {
            const unsigned* slot = ws + s * 8;
            unsigned w0, w1, w2, w3, w4;
            int spins = 0;
            while (true) {
                w4 = __hip_atomic_load(slot + 4, __ATOMIC_ACQUIRE, __HIP_MEMORY_SCOPE_AGENT);
                w0 = __hip_atomic_load(slot + 0, __ATOMIC_RELAXED, __HIP_MEMORY_SCOPE_AGENT);
                w1 = __hip_atomic_load(slot + 1, __ATOMIC_RELAXED, __HIP_MEMORY_SCOPE_AGENT);
                w2 = __hip_atomic_load(slot + 2, __ATOMIC_RELAXED, __HIP_MEMORY_SCOPE_AGENT);
                w3 = __hip_atomic_load(slot + 3, __ATOMIC_RELAXED, __HIP_MEMORY_SCOPE_AGENT);
                if (mixh(w0, w1, w2, w3) == w4) break;
                if (++spins > (1 << 24)) break;   // bail rather than hang
            }
            s1  += (double)__uint_as_float(w0);
            s3  += (double)__uint_as_float(w1);
            s2  += (double)__uint_as_float(w2);
            s0d += (double)__uint_as_float(w3);
        }
        for (int off = 32; off > 0; off >>= 1) {
            s1  += __shfl_down(s1, off);
            s3  += __shfl_down(s3, off);
            s2  += __shfl_down(s2, off);
            s0d += __shfl_down(s0d, off);
        }
        __shared__ double d1[4], d3[4], d2[4], d0[4];
        if (lane == 0) { d1[wid] = s1; d3[wid] = s3; d2[wid] = s2; d0[wid] = s0d; }
        __syncthreads();
        if (tid == 0) {
            double t1 = d1[0]+d1[1]+d1[2]+d1[3];
            double t3 = d3[0]+d3[1]+d3[2]+d3[3];
            double t2 = d2[0]+d2[1]+d2[2]+d2[3];
            double t0 = d0[0]+d0[1]+d0[2]+d0[3];
            double n2 = (double)BN * (double)BN;
            double l0 = t0 / (double)BN;
            double l1 = (1e-4 + t1) / n2;
            double l2 = (1e-4 + t2) / n2;
            double l3 = (1e-4 + t3) / n2;
            out[0] = (float)((l0 + l1) + (l2 + l3));
            out[1] = (float)l0;
            out[2] = (float)l1;
            out[3] = (float)l2;
            out[4] = (float)l3;
        }
    }
}

extern "C" void kernel_launch(void* const* d_in, const int* in_sizes, int n_in,
                              void* d_out, int out_size, void* d_ws, size_t ws_size,
                              hipStream_t stream) {
    const float* src = (const float*)d_in[0];
    const int*   tgt = (const int*)d_in[1];
    float*       out = (float*)d_out;
    unsigned*     ws = (unsigned*)d_ws;   // NB*8 words, every slot rewritten every call

    k_all<<<dim3(GX, GY), 256, 0, stream>>>(src, tgt, ws, out);
}

// Round 6
// 14.742 us; speedup vs baseline: 3.6874x; 1.1494x over previous
//
#include <hip/hip_runtime.h>
#include <math.h>

#define BN   4096
#define GX   16          // i-tiles of 256 rows
#define GY   32          // j-tiles of 128 rows
#define TJ   128         // j-tile size
#define NB   (GX * GY)   // 512 partial slots

// ln(1e-4)
#define LOGE  (-9.210340371976184f)
#define EPSF  (1e-4f)
// sT = 2*eps*ln(eps), constant for every row
#define STC   (2.0f * EPSF * LOGE)

typedef float f32x2 __attribute__((ext_vector_type(2)));
__device__ __forceinline__ f32x2 sp(float v) { return (f32x2){v, v}; }

// partial[bid*4 + {0,1,2,3}] = {a1, a3, c2, c0}
__global__ __launch_bounds__(256) void k_pairs(const float* __restrict__ src,
                                               const int* __restrict__ tgt,
                                               float* __restrict__ partial) {
    __shared__ float Lxs[TJ], Lys[TJ], Lzs[TJ];   // class-segmented SoA
    __shared__ int   sc[3], off[3], rk[3];
    __shared__ float4 wred[4];
    int tid = threadIdx.x;
    int bx = blockIdx.x, by = blockIdx.y;

    if (tid < 3) { sc[tid] = 0; rk[tid] = 0; }

    // ---- this thread's i-row data (registers only) ----
    int i = bx * 256 + tid;
    float nS0, nS1, nS2, aI, sumLS_i, L0i, L1i, L2i;
    int ti;
    {
        float x0 = src[3*i], x1 = src[3*i+1], x2 = src[3*i+2];
        float m  = fmaxf(x0, fmaxf(x1, x2));
        float e0 = expf(x0 - m), e1 = expf(x1 - m), e2 = expf(x2 - m);
        float s  = e0 + e1 + e2;
        float inv = 1.0f / s;
        float S0 = e0 * inv, S1 = e1 * inv, S2 = e2 * inv;
        float ls = logf(s);
        L0i = x0 - m - ls; L1i = x1 - m - ls; L2i = x2 - m - ls;
        sumLS_i = L0i + L1i + L2i;
        float sS = S0 * L0i + S1 * L1i + S2 * L2i;
        ti = tgt[i];
        aI = sS - STC;                 // sS_i - sT
        nS0 = -S0; nS1 = -S1; nS2 = -S2;
    }
    // loss_1 segment constants: e1 = |g + c|, c by class match
    float cSame = 2.0f * EPSF * LOGE;
    float cDiff = (1.0f + EPSF) * LOGE;
    // e3 = |g + w.L_j|, w_k = eps + (1-eps)[k==ti]
    float w0 = EPSF + ((ti == 0) ? (1.0f - EPSF) : 0.0f);
    float w1 = EPSF + ((ti == 1) ? (1.0f - EPSF) : 0.0f);
    float w2 = EPSF + ((ti == 2) ? (1.0f - EPSF) : 0.0f);
    // loss_2 per-class |u_ik|
    float base = EPSF * (2.0f * LOGE - sumLS_i);
    float au0 = fabsf(base + (1.0f - EPSF) * (((ti == 0) ? 0.f : LOGE) - L0i));
    float au1 = fabsf(base + (1.0f - EPSF) * (((ti == 1) ? 0.f : LOGE) - L1i));
    float au2 = fabsf(base + (1.0f - EPSF) * (((ti == 2) ? 0.f : LOGE) - L2i));
    // loss_0 per-row (counted once: only by==0 blocks)
    float LSt = (ti == 0) ? L0i : ((ti == 1) ? L1i : L2i);
    float c0 = (by == 0) ? -(EPSF * sumLS_i + (1.0f - EPSF) * LSt) : 0.0f;

    __syncthreads();   // sc/rk zeroed

    // ---- stage j-tile: pass 1 count classes ----
    int tj = -1;
    float jL0 = 0.f, jL1 = 0.f, jL2 = 0.f;
    if (tid < TJ) {
        int j = by * TJ + tid;
        float x0 = src[3*j], x1 = src[3*j+1], x2 = src[3*j+2];
        float m  = fmaxf(x0, fmaxf(x1, x2));
        float e0 = expf(x0 - m), e1 = expf(x1 - m), e2 = expf(x2 - m);
        float s  = e0 + e1 + e2;
        float ls = logf(s);
        jL0 = x0 - m - ls; jL1 = x1 - m - ls; jL2 = x2 - m - ls;
        tj = tgt[j];
        atomicAdd(&sc[tj], 1);
    }
    __syncthreads();
    if (tid == 0) { off[0] = 0; off[1] = sc[0]; off[2] = sc[0] + sc[1]; }
    __syncthreads();
    // ---- pass 2: scatter into class-segmented SoA ----
    if (tid < TJ) {
        int r = atomicAdd(&rk[tj], 1);
        int pos = off[tj] + r;
        Lxs[pos] = jL0; Lys[pos] = jL1; Lzs[pos] = jL2;
    }
    __syncthreads();

    // loss_2: local j-tile counts x per-class |u|
    float c2 = (float)sc[0] * au0 + (float)sc[1] * au1 + (float)sc[2] * au2;

    // ---- pair loop, per class segment (packed 2xf32, 4 j per round) ----
    f32x2 nS0v = sp(nS0), nS1v = sp(nS1), nS2v = sp(nS2), aIv = sp(aI);
    f32x2 w0v = sp(w0), w1v = sp(w1), w2v = sp(w2);
    f32x2 acc1v = sp(0.f), acc3v = sp(0.f);
    float a1s = 0.f, a3s = 0.f;

    const float4* Lx4 = reinterpret_cast<const float4*>(Lxs);
    const float4* Ly4 = reinterpret_cast<const float4*>(Lys);
    const float4* Lz4 = reinterpret_cast<const float4*>(Lzs);

    for (int s = 0; s < 3; ++s) {
        int k   = off[s];
        int end = k + sc[s];
        float cseg = (s == ti) ? cSame : cDiff;
        f32x2 cv = sp(cseg);
        // scalar head to 4-alignment
        while (k < end && (k & 3)) {
            float g = fmaf(nS0, Lxs[k], fmaf(nS1, Lys[k], fmaf(nS2, Lzs[k], aI)));
            a1s += fabsf(g + cseg);
            a3s += fabsf(fmaf(w0, Lxs[k], fmaf(w1, Lys[k], fmaf(w2, Lzs[k], g))));
            ++k;
        }
        // packed main: 4 j's per round
        #pragma unroll 2
        while (k + 3 < end) {
            int p = k >> 2;
            float4 qx = Lx4[p], qy = Ly4[p], qz = Lz4[p];   // broadcast reads
            f32x2 lx, ly, lz, g, t, e;
            // halves 01 and 23
            lx = (f32x2){qx.x, qx.y}; ly = (f32x2){qy.x, qy.y}; lz = (f32x2){qz.x, qz.y};
            g = __builtin_elementwise_fma(nS2v, lz, aIv);
            g = __builtin_elementwise_fma(nS1v, ly, g);
            g = __builtin_elementwise_fma(nS0v, lx, g);
            t = g + cv;
            acc1v += __builtin_elementwise_max(t, -t);
            e = __builtin_elementwise_fma(w2v, lz, g);
            e = __builtin_elementwise_fma(w1v, ly, e);
            e = __builtin_elementwise_fma(w0v, lx, e);
            acc3v += __builtin_elementwise_max(e, -e);
            lx = (f32x2){qx.z, qx.w}; ly = (f32x2){qy.z, qy.w}; lz = (f32x2){qz.z, qz.w};
            g = __builtin_elementwise_fma(nS2v, lz, aIv);
            g = __builtin_elementwise_fma(nS1v, ly, g);
            g = __builtin_elementwise_fma(nS0v, lx, g);
            t = g + cv;
            acc1v += __builtin_elementwise_max(t, -t);
            e = __builtin_elementwise_fma(w2v, lz, g);
            e = __builtin_elementwise_fma(w1v, ly, e);
            e = __builtin_elementwise_fma(w0v, lx, e);
            acc3v += __builtin_elementwise_max(e, -e);
            k += 4;
        }
        // scalar tail
        while (k < end) {
            float g = fmaf(nS0, Lxs[k], fmaf(nS1, Lys[k], fmaf(nS2, Lzs[k], aI)));
            a1s += fabsf(g + cseg);
            a3s += fabsf(fmaf(w0, Lxs[k], fmaf(w1, Lys[k], fmaf(w2, Lzs[k], g))));
            ++k;
        }
    }
    float a1 = acc1v.x + acc1v.y + a1s;
    float a3 = acc3v.x + acc3v.y + a3s;

    // ---- block reduction via wave shuffles ----
    for (int o = 32; o > 0; o >>= 1) {
        a1 += __shfl_down(a1, o);
        a3 += __shfl_down(a3, o);
        c2 += __shfl_down(c2, o);
        c0 += __shfl_down(c0, o);
    }
    int lane = tid & 63, wid = tid >> 6;
    if (lane == 0) wred[wid] = make_float4(a1, a3, c2, c0);
    __syncthreads();
    if (tid == 0) {
        float4 p = wred[0];
        #pragma unroll
        for (int w = 1; w < 4; ++w) {
            p.x += wred[w].x; p.y += wred[w].y;
            p.z += wred[w].z; p.w += wred[w].w;
        }
        int bid = by * GX + bx;
        *reinterpret_cast<float4*>(partial + bid * 4) = p;
    }
}

// ---------------- kernel 2: reduce partials, finalize ----------------
__global__ __launch_bounds__(512) void k_final(const float* __restrict__ partial,
                                               float* __restrict__ out) {
    __shared__ double s1[512], s3[512], s2[512], s0[512];
    int tid = threadIdx.x;
    float4 p = *reinterpret_cast<const float4*>(partial + tid * 4);
    s1[tid] = (double)p.x; s3[tid] = (double)p.y;
    s2[tid] = (double)p.z; s0[tid] = (double)p.w;
    __syncthreads();
    for (int s = 256; s > 0; s >>= 1) {
        if (tid < s) {
            s1[tid] += s1[tid + s]; s3[tid] += s3[tid + s];
            s2[tid] += s2[tid + s]; s0[tid] += s0[tid + s];
        }
        __syncthreads();
    }
    if (tid == 0) {
        double n2 = (double)BN * (double)BN;
        double l0 = s0[0] / (double)BN;
        double l1 = (1e-4 + s1[0]) / n2;
        double l2 = (1e-4 + s2[0]) / n2;
        double l3 = (1e-4 + s3[0]) / n2;
        out[0] = (float)((l0 + l1) + (l2 + l3));
        out[1] = (float)l0;
        out[2] = (float)l1;
        out[3] = (float)l2;
        out[4] = (float)l3;
    }
}

extern "C" void kernel_launch(void* const* d_in, const int* in_sizes, int n_in,
                              void* d_out, int out_size, void* d_ws, size_t ws_size,
                              hipStream_t stream) {
    const float* src = (const float*)d_in[0];
    const int*   tgt = (const int*)d_in[1];
    float*       out = (float*)d_out;
    float*   partial = (float*)d_ws;    // NB*4 floats, fully rewritten every call

    k_pairs<<<dim3(GX, GY), 256, 0, stream>>>(src, tgt, partial);
    k_final<<<1, 512, 0, stream>>>(partial, out);
}